// Round 2
// baseline (752.473 us; speedup 1.0000x reference)
//
#include <hip/hip_runtime.h>

// Cosine similarity of each pixel's C=128 vector with its 8 neighbors (3x3,
// zero-padded), minus 1.  Identity: out = dot(xn, boxsum3x3(xn)) - 1, with
// the box sum separable: H = horizontal 3-sum of xn, vertical 3-sum rolled
// through registers row by row.
//
// R2 (vs ~365us kernel): direct-to-LDS staging via global_load_lds (no VGPR
// round trip), raw tile + per-pixel 1/norm table instead of storing xn,
// SOUT=32 -> 48KiB LDS -> 3 blocks/CU (6 waves/SIMD), uniform vmcnt
// discipline (pad lanes reload an L1-hot address).

#define HH 1024
#define WW 1024
#define C4 32                    // float4 chunks per pixel (128 channels)
#define SOUT 32                  // output columns per strip
#define SHALO (SOUT + 2)         // 34 pixels incl. x halo
#define RROWS 32                 // output rows per block
#define NT 512
#define NVALID (SHALO * C4)      // 1088 float4 entries per staged row
#define NSTAGE 3                 // ceil(NVALID / NT)
#define NPAD (NSTAGE * NT)       // 1536 entries (pad keeps vmcnt uniform)
#define OWN ((SOUT * C4) / NT)   // 2 owned (x,chunk) pairs per thread

__device__ __forceinline__ float dot4(float4 a, float4 b) {
    return fmaf(a.x, b.x, fmaf(a.y, b.y, fmaf(a.z, b.z, a.w * b.w)));
}

// Issue NSTAGE async global->LDS loads for input row y (clamped to [0,ymax]).
// No VGPR payload; the wait is a counted vmcnt one iteration later.  Pad
// entries (idx >= NVALID) re-load this thread's i=0 address: L1 hit, no
// extra HBM, and every wave issues exactly NSTAGE vmem ops.
__device__ __forceinline__ void stage(const float4* __restrict__ in,
                                      int y, int ymax, int x0, int t,
                                      float4* dst /* LDS row buffer */) {
    const int yc = min(max(y, 0), ymax);
    const size_t rowbase = (size_t)yc * WW * C4;
#pragma unroll
    for (int i = 0; i < NSTAGE; ++i) {
        const int idx  = t + i * NT;
        const int eidx = (idx < NVALID) ? idx : (idx - 2 * NT);  // pad -> dup
        const int gx   = x0 - 1 + (eidx >> 5);
        const int gxc  = min(max(gx, 0), WW - 1);
        const float4* src = in + rowbase + (size_t)gxc * C4 + (eidx & 31);
        __builtin_amdgcn_global_load_lds(
            (const __attribute__((address_space(1))) void*)src,
            (__attribute__((address_space(3))) void*)(dst + idx), 16, 0, 0);
    }
}

__global__ __launch_bounds__(NT, 6)
void cos_sim_kernel(const float4* __restrict__ in, float* __restrict__ out) {
    __shared__ float4 raw[2][NPAD];        // 2 x 24 KiB raw rows (ping-pong)
    __shared__ float  invn[2][SHALO];      // per-pixel 1/norm

    const int t   = threadIdx.x;
    const int c4  = t & 31;                // channel chunk within pixel
    const int xo0 = t >> 5;                // base owned output col (0..15)
    const int x0  = blockIdx.x * SOUT;
    const int r0  = blockIdx.y * RROWS;
    const int ylast = r0 + RROWS;
    const int ymax  = min(ylast, HH - 1);  // clamp target for staging

    float4 Hprev[OWN], XNprev[OWN];
    float  accP[OWN];
#pragma unroll
    for (int i = 0; i < OWN; ++i) {
        Hprev[i]  = make_float4(0.f, 0.f, 0.f, 0.f);
        XNprev[i] = make_float4(0.f, 0.f, 0.f, 0.f);
        accP[i]   = 0.f;
    }

    stage(in, r0 - 1, ymax, x0, t, &raw[0][0]);

    int cb = 0;
    for (int y = r0 - 1; y <= ylast; ++y) {
        // Row y (issued one full iteration ago) has landed in raw[cb]; the
        // barrier also guarantees everyone is done reading raw[cb^1].
        asm volatile("s_waitcnt vmcnt(0)" ::: "memory");
        __builtin_amdgcn_s_barrier();

        // Fire-and-forget next row into the other buffer; in flight across
        // the whole normalize+compute phase below.
        stage(in, y + 1, ymax, x0, t, &raw[cb ^ 1][0]);

        // Zero OOB halo slots (matches zero padding) + per-pixel 1/norm via
        // 32-lane xor reduce.  Each thread fixes/reads only its own slots.
        const bool rowOK = (y >= 0) && (y < HH);
#pragma unroll
        for (int i = 0; i < NSTAGE; ++i) {
            const int idx = t + i * NT;
            if (idx < NVALID) {            // wave-uniform (NVALID % 64 == 0)
                const int gx = x0 - 1 + (idx >> 5);
                float4 v;
                if (!rowOK || gx < 0 || gx >= WW) {
                    v = make_float4(0.f, 0.f, 0.f, 0.f);
                    raw[cb][idx] = v;      // fix LDS for the compute phase
                } else {
                    v = raw[cb][idx];
                }
                float s = dot4(v, v);
                s += __shfl_xor(s, 1);
                s += __shfl_xor(s, 2);
                s += __shfl_xor(s, 4);
                s += __shfl_xor(s, 8);
                s += __shfl_xor(s, 16);
                if (c4 == 0) invn[cb][idx >> 5] = rsqrtf(fmaxf(s, 1e-16f));
            }
        }
        asm volatile("s_waitcnt lgkmcnt(0)" ::: "memory");
        __builtin_amdgcn_s_barrier();

        // Compute: H_y = a*ia + b*ib + r*ir from raw + inv table, roll the
        // vertical 3-sum in registers, finalize output row y-1.
#pragma unroll
        for (int i = 0; i < OWN; ++i) {
            const int xo = xo0 + 16 * i;
            const float4 a = raw[cb][(xo    ) * C4 + c4];
            const float4 b = raw[cb][(xo + 1) * C4 + c4];
            const float4 r = raw[cb][(xo + 2) * C4 + c4];
            const float ia = invn[cb][xo];
            const float ib = invn[cb][xo + 1];
            const float ir = invn[cb][xo + 2];
            float4 Hc;
            Hc.x = fmaf(a.x, ia, fmaf(b.x, ib, r.x * ir));
            Hc.y = fmaf(a.y, ia, fmaf(b.y, ib, r.y * ir));
            Hc.z = fmaf(a.z, ia, fmaf(b.z, ib, r.z * ir));
            Hc.w = fmaf(a.w, ia, fmaf(b.w, ib, r.w * ir));
            const float4 xb = make_float4(b.x * ib, b.y * ib,
                                          b.z * ib, b.w * ib);

            float fin = accP[i] + dot4(XNprev[i], Hc);
            accP[i]   = dot4(xb, Hprev[i]) + dot4(xb, Hc);
            XNprev[i] = xb;
            Hprev[i]  = Hc;

            if (y > r0) {                  // uniform: finalize row y-1
                fin += __shfl_xor(fin, 1);
                fin += __shfl_xor(fin, 2);
                fin += __shfl_xor(fin, 4);
                fin += __shfl_xor(fin, 8);
                fin += __shfl_xor(fin, 16);
                if (c4 == 0) {
                    out[(size_t)(y - 1) * WW + x0 + xo] = fin - 1.0f;
                }
            }
        }
        cb ^= 1;
    }
}

extern "C" void kernel_launch(void* const* d_in, const int* in_sizes, int n_in,
                              void* d_out, int out_size, void* d_ws, size_t ws_size,
                              hipStream_t stream) {
    const float4* in = (const float4*)d_in[0];
    float* out = (float*)d_out;
    dim3 grid(WW / SOUT, HH / RROWS);   // 32 x 32 = 1024 blocks
    cos_sim_kernel<<<grid, NT, 0, stream>>>(in, out);
}

// Round 4
// 712.617 us; speedup vs baseline: 1.0559x; 1.0559x over previous
//
#include <hip/hip_runtime.h>

// Cosine similarity of each pixel's C=128 vector with its 8 neighbors (3x3,
// zero-padded), minus 1.  Identity: out = dot(xn, boxsum3x3(xn)) - 1 with the
// box sum separable: H = horizontal 3-sum of xn (lane-local here), vertical
// 3-sum rolled through registers row by row.
//
// R3 (resubmitted R4: previous bench was an infra double-fault, kernel never
// ran).  Barrier-free, LDS-free decomposition.  Each WAVE owns 2 output
// columns x 64 rows and walks down, holding all rolling state in registers:
//  - per row: 3 coalesced 1KB loads (pixel pairs L/C/R); halo pixels dedup in
//    L1/L2 (each pixel HBM-fetched once, ~528MB total -> ~84us floor)
//  - lane = channel chunk, half-wave = pixel -> H = xnL+xnC+xnR needs NO
//    cross-lane traffic; only 3 norm reduces + 1 output reduce per row
//  - depth-2 register prefetch (issue y+2 while processing y), no barriers,
//    24 waves/CU -> latency hidden by TLP+MLP, memory pipe never drains
//  - bijective XCD swizzle so column-neighbor blocks share an L2

#define HH 1024
#define WW 1024
#define C4 32                    // float4 chunks per pixel (128 channels)
#define ROWF4 (WW * C4)          // float4 elements per image row
#define SEGROWS 64               // output rows per wave
#define NSEG (HH / SEGROWS)      // 16 row segments
#define NT 256                   // 4 waves per block, 8 columns per block
#define NBLK ((WW / 8) * NSEG)   // 128 col-groups x 16 segs = 2048 blocks

__device__ __forceinline__ float dot4(float4 a, float4 b) {
    return fmaf(a.x, b.x, fmaf(a.y, b.y, fmaf(a.z, b.z, a.w * b.w)));
}

__device__ __forceinline__ float wsum32(float s) {
    s += __shfl_xor(s, 1);
    s += __shfl_xor(s, 2);
    s += __shfl_xor(s, 4);
    s += __shfl_xor(s, 8);
    s += __shfl_xor(s, 16);
    return s;
}

__global__ __launch_bounds__(NT, 6)
void cos_sim_kernel(const float4* __restrict__ in, float* __restrict__ out) {
    const int tid  = threadIdx.x;
    const int lane = tid & 63;
    const int wv   = tid >> 6;       // wave in block: 0..3
    const int cl   = lane & 31;      // channel chunk 0..31
    const int hf   = lane >> 5;      // pixel within pair: 0/1

    // Bijective XCD swizzle (NBLK % 8 == 0): each XCD gets a contiguous
    // range of logical ids -> column-neighbor blocks share an L2.
    const int bid = blockIdx.x;
    const int lg  = (bid & 7) * (NBLK / 8) + (bid >> 3);
    const int colgrp = lg & 127;     // 8-column group
    const int yseg   = lg >> 7;      // row segment

    const int x0    = colgrp * 8 + wv * 2;   // even; own columns x0, x0+1
    const int rbase = yseg * SEGROWS;
    const int ymax  = min(rbase + SEGROWS, HH - 1);  // prefetch clamp row

    // Per-lane column offsets (float4 units) for the three pixel-pair loads:
    // L=(x0-1,x0)  C=(x0,x0+1)  R=(x0+1,x0+2); OOB x clamped, zeroed below.
    const int xL = x0 - 1 + hf;
    const int xR = x0 + 1 + hf;
    const bool okL = (xL >= 0);
    const bool okR = (xR < WW);
    const int offL = max(xL, 0) * C4 + cl;
    const int offC = (x0 + hf) * C4 + cl;
    const int offR = min(xR, WW - 1) * C4 + cl;

    float4 XNp = make_float4(0.f, 0.f, 0.f, 0.f);   // xn of previous row
    float4 Hp  = make_float4(0.f, 0.f, 0.f, 0.f);   // H of previous row
    float  accP = 0.f;                              // partial for row y-1

    // Prologue: rows rbase-1 (addr-clamped; value masked by oky) and rbase.
    const size_t pb0 = (size_t)max(rbase - 1, 0) * ROWF4;
    const size_t pb1 = (size_t)rbase * ROWF4;
    float4 l0 = in[pb0 + offL], c0 = in[pb0 + offC], q0 = in[pb0 + offR];
    float4 l1 = in[pb1 + offL], c1 = in[pb1 + offC], q1 = in[pb1 + offR];

#pragma unroll 2
    for (int i = 0; i < SEGROWS + 2; ++i) {
        const int y  = rbase - 1 + i;
        const int yp = min(y + 2, ymax);      // prefetch row (dups are L1-hot)
        const size_t pb = (size_t)yp * ROWF4;
        float4 nl = in[pb + offL];            // issued before row y is used:
        float4 nc = in[pb + offC];            // depth-2 pipeline, counted
        float4 nr = in[pb + offR];            // vmcnt waits by the compiler

        const bool oky = (y >= 0) && (y < HH);
        const float4 Z = make_float4(0.f, 0.f, 0.f, 0.f);
        const float4 L = (oky && okL) ? l0 : Z;
        const float4 Cc = oky ? c0 : Z;
        const float4 R = (oky && okR) ? q0 : Z;

        // Per-pixel inv norms (both half-waves reduce their own pixel).
        const float iL = rsqrtf(fmaxf(wsum32(dot4(L, L)),   1e-16f));
        const float iC = rsqrtf(fmaxf(wsum32(dot4(Cc, Cc)), 1e-16f));
        const float iR = rsqrtf(fmaxf(wsum32(dot4(R, R)),   1e-16f));

        // xn of own column and lane-local horizontal 3-sum H.
        float4 xc, H;
        xc.x = Cc.x * iC; xc.y = Cc.y * iC; xc.z = Cc.z * iC; xc.w = Cc.w * iC;
        H.x = fmaf(L.x, iL, fmaf(R.x, iR, xc.x));
        H.y = fmaf(L.y, iL, fmaf(R.y, iR, xc.y));
        H.z = fmaf(L.z, iL, fmaf(R.z, iR, xc.z));
        H.w = fmaf(L.w, iL, fmaf(R.w, iR, xc.w));

        // Vertical roll: finalize out row y-1, start/extend row y.
        float fin = accP + dot4(XNp, H);
        accP = dot4(xc, Hp) + dot4(xc, H);
        XNp = xc; Hp = H;

        if (y > rbase) {                      // block-uniform branch
            fin = wsum32(fin);
            if (cl == 0) {                    // lanes 0 and 32 store
                out[(size_t)(y - 1) * WW + x0 + hf] = fin - 1.0f;
            }
        }

        // Rotate the pipeline (renamed away under unroll 2).
        l0 = l1; c0 = c1; q0 = q1;
        l1 = nl; c1 = nc; q1 = nr;
    }
}

extern "C" void kernel_launch(void* const* d_in, const int* in_sizes, int n_in,
                              void* d_out, int out_size, void* d_ws, size_t ws_size,
                              hipStream_t stream) {
    const float4* in = (const float4*)d_in[0];
    float* out = (float*)d_out;
    cos_sim_kernel<<<dim3(NBLK), dim3(NT), 0, stream>>>(in, out);
}

// Round 5
// 699.236 us; speedup vs baseline: 1.0761x; 1.0191x over previous
//
#include <hip/hip_runtime.h>

// Cosine similarity of each pixel's C=128 vector with its 8 neighbors (3x3,
// zero-padded), minus 1.  Identity: out = dot(xn, boxsum3x3(xn)) - 1.
// Single pass over the 512 MiB input -> HBM-read-bound (~85 us kernel floor).
//
// R5 = byte-identical restore of R1 (best measured: 699.8 us).  Session
// evidence: four structurally disjoint schedules (barrier-locked LDS loop,
// double-buffered variant, global_load_lds variant, barrier-free register
// walk) all land at 700-752 us; the profile shows ~620 us of in-window
// harness work (2 GiB workspace-poison fill at ~335 us + dozens of reset
// memsets), so the kernel component here is already at the ~85 us HBM read
// floor.  Schedule: one-row-ahead register prefetch, ping-pong LDS row
// buffer, single lgkmcnt-only barrier per row (prefetch loads stay in
// flight across it), rsqrtf normalize.

#define HH 1024
#define WW 1024
#define C4 32          // float4 chunks per pixel (128 channels)
#define SOUT 64        // output columns per strip
#define SHALO (SOUT + 2)
#define RROWS 32       // output rows per block
#define NT 512
#define NSTAGE ((SHALO * C4 + NT - 1) / NT)   // 5 (last partial)
#define OWN ((SOUT * C4) / NT)                // 4 owned (x,chunk) per thread

__device__ __forceinline__ float dot4(float4 a, float4 b) {
    return fmaf(a.x, b.x, fmaf(a.y, b.y, fmaf(a.z, b.z, a.w * b.w)));
}

__device__ __forceinline__ void stage_row(const float4* __restrict__ in,
                                          int y, int x0, int t, bool need,
                                          float4 (&v)[NSTAGE]) {
#pragma unroll
    for (int i = 0; i < NSTAGE; ++i) {
        const int idx = t + i * NT;          // (x_in, chunk) flat
        float4 val = make_float4(0.f, 0.f, 0.f, 0.f);
        const bool inR = (i < NSTAGE - 1) || (idx < SHALO * C4);
        if (inR) {
            const int gx = x0 - 1 + (idx >> 5);
            if (need && gx >= 0 && gx < WW) {
                val = in[(size_t)(y * WW + gx) * C4 + (idx & 31)];
            }
        }
        v[i] = val;
    }
}

__global__ __launch_bounds__(NT, 4)
void cos_sim_kernel(const float4* __restrict__ in, float* __restrict__ out) {
    // Two row buffers (ping-pong): write buf, barrier, read buf; next row
    // writes buf^1 so no read->write barrier is needed.
    __shared__ float4 xrow[2][SHALO * C4];

    const int t   = threadIdx.x;
    const int c4  = t & 31;       // channel chunk within pixel
    const int xo0 = t >> 5;       // base owned output col (0..15), +16*i
    const int x0  = blockIdx.x * SOUT;   // strip base (output cols)
    const int r0  = blockIdx.y * RROWS;  // row-chunk base
    const int ylast = r0 + RROWS;

    // Rolling per-owned-pixel state: H of previous input row, xn of previous
    // input row, and the partial accumulator for output row (y-1).
    float4 Hprev[OWN], XNprev[OWN];
    float  accP[OWN];
#pragma unroll
    for (int i = 0; i < OWN; ++i) {
        Hprev[i]  = make_float4(0.f, 0.f, 0.f, 0.f);
        XNprev[i] = make_float4(0.f, 0.f, 0.f, 0.f);
        accP[i]   = 0.f;
    }

    float4 vA[NSTAGE], vB[NSTAGE];
    stage_row(in, r0 - 1, x0, t, (r0 - 1 >= 0), vA);

    int buf = 0;
    for (int y = r0 - 1; y <= ylast; ++y) {
        // ---- issue next row's loads NOW; waited on at the vA=vB copy at
        //      iteration end -> latency hidden under normalize+compute ----
        const int yn = y + 1;
        stage_row(in, yn, x0, t,
                  (yn >= 0) && (yn < HH) && (yn <= ylast), vB);

        // ---- normalize vA: per-pixel norm via 32-lane xor reduce -> LDS ----
#pragma unroll
        for (int i = 0; i < NSTAGE; ++i) {
            const int idx = t + i * NT;
            float s = dot4(vA[i], vA[i]);
            s += __shfl_xor(s, 1);
            s += __shfl_xor(s, 2);
            s += __shfl_xor(s, 4);
            s += __shfl_xor(s, 8);
            s += __shfl_xor(s, 16);
            // rsqrtf(max(s,1e-16)) == 1/max(sqrt(s),1e-8) (same clamp), but
            // ~5x fewer VALU ops than precise sqrt + precise divide.
            const float inv = rsqrtf(fmaxf(s, 1e-16f));
            const bool inR = (i < NSTAGE - 1) || (idx < SHALO * C4);
            if (inR) {
                float4 w;
                w.x = vA[i].x * inv; w.y = vA[i].y * inv;
                w.z = vA[i].z * inv; w.w = vA[i].w * inv;
                xrow[buf][idx] = w;
            }
        }

        // LDS-writes-only drain + raw barrier: prefetch (vmcnt) stays in
        // flight across the barrier, unlike __syncthreads' vmcnt(0) drain.
        asm volatile("s_waitcnt lgkmcnt(0)" ::: "memory");
        __builtin_amdgcn_s_barrier();

        // ---- compute: H_y in registers, pair with rolling xn/H state ----
#pragma unroll
        for (int i = 0; i < OWN; ++i) {
            const int xo = xo0 + 16 * i;                     // output col
            const float4 a = xrow[buf][(xo    ) * C4 + c4];  // x-1
            const float4 b = xrow[buf][(xo + 1) * C4 + c4];  // x   (center)
            const float4 r = xrow[buf][(xo + 2) * C4 + c4];  // x+1
            float4 Hc;
            Hc.x = a.x + b.x + r.x; Hc.y = a.y + b.y + r.y;
            Hc.z = a.z + b.z + r.z; Hc.w = a.w + b.w + r.w;

            // out(y-1) completes: += dot(xn_{y-1}, H_y)
            float fin = accP[i] + dot4(XNprev[i], Hc);
            // out(y) partial: dot(xn_y, H_{y-1}) + dot(xn_y, H_y)
            accP[i]   = dot4(b, Hprev[i]) + dot4(b, Hc);
            XNprev[i] = b;
            Hprev[i]  = Hc;

            if (y > r0) {   // uniform branch: finalize row y-1 (in range)
                fin += __shfl_xor(fin, 1);
                fin += __shfl_xor(fin, 2);
                fin += __shfl_xor(fin, 4);
                fin += __shfl_xor(fin, 8);
                fin += __shfl_xor(fin, 16);
                if (c4 == 0) {
                    out[(size_t)(y - 1) * WW + x0 + xo] = fin - 1.0f;
                }
            }
        }

        buf ^= 1;
        // The copy is where the compiler waits on vB's loads -> the wait
        // lands a full iteration after issue.
#pragma unroll
        for (int i = 0; i < NSTAGE; ++i) vA[i] = vB[i];
    }
}

extern "C" void kernel_launch(void* const* d_in, const int* in_sizes, int n_in,
                              void* d_out, int out_size, void* d_ws, size_t ws_size,
                              hipStream_t stream) {
    const float4* in = (const float4*)d_in[0];
    float* out = (float*)d_out;
    dim3 grid(WW / SOUT, HH / RROWS);   // 16 x 32 = 512 blocks
    cos_sim_kernel<<<grid, NT, 0, stream>>>(in, out);
}